// Round 5
// baseline (272.969 us; speedup 1.0000x reference)
//
#include <hip/hip_runtime.h>

#define Bsz 128
#define Tsz 256
#define Nsz 128
#define Asz 512
#define Vsz 512

typedef __attribute__((ext_vector_type(8))) short bh8;
typedef __attribute__((ext_vector_type(4))) float f32x4;

__device__ __forceinline__ unsigned short f2bf(float x) {
  unsigned int u = __float_as_uint(x);
  return (unsigned short)((u + 0x7fffu + ((u >> 16) & 1u)) >> 16);
}
__device__ __forceinline__ float bf2f(unsigned short h) {
  return __uint_as_float(((unsigned int)h) << 16);
}
__device__ __forceinline__ float fast_tanh(float x) {
  float ax = fabsf(x);
  float e = __expf(-2.f * ax);
  float t = (1.f - e) / (1.f + e);
  return copysignf(t, x);
}

// async global->LDS, 16B/lane; LDS dest = wave-uniform base (+lane*16 implicit)
__device__ __forceinline__ void gld16(const void* g, void* l) {
  __builtin_amdgcn_global_load_lds(
      (const __attribute__((address_space(1))) unsigned int*)g,
      (__attribute__((address_space(3))) unsigned int*)l, 16, 0, 0);
}

// truncation split of 8 f32 into hi/lo bf16 fragments
struct Frag2 { bh8 hi, lo; };
__device__ __forceinline__ Frag2 split8(float4 x0, float4 x1) {
  float xs[8] = {x0.x, x0.y, x0.z, x0.w, x1.x, x1.y, x1.z, x1.w};
  union { unsigned int u[4]; bh8 v; } H, L;
#pragma unroll
  for (int i = 0; i < 4; ++i) {
    unsigned int a = __float_as_uint(xs[2 * i]);
    unsigned int b = __float_as_uint(xs[2 * i + 1]);
    H.u[i] = (a >> 16) | (b & 0xffff0000u);
    float la = xs[2 * i]     - __uint_as_float(a & 0xffff0000u);
    float lb = xs[2 * i + 1] - __uint_as_float(b & 0xffff0000u);
    L.u[i] = (__float_as_uint(la) >> 16) | (__float_as_uint(lb) & 0xffff0000u);
  }
  Frag2 r; r.hi = H.v; r.lo = L.v; return r;
}
__device__ __forceinline__ float dot8(float4 x0, float4 x1, float4 w0, float4 w1) {
  return x0.x*w0.x + x0.y*w0.y + x0.z*w0.z + x0.w*w0.w
       + x1.x*w1.x + x1.y*w1.y + x1.z*w1.z + x1.w*w1.w;
}

// W^T -> hi/lo bf16 (converted ONCE); 64 blocks
__global__ __launch_bounds__(256) void prep_wt(
    const float* __restrict__ W, unsigned short* __restrict__ WT_hi,
    unsigned short* __restrict__ WT_lo)
{
  __shared__ float t[64][65];
  int tid = threadIdx.x;
  int bb = blockIdx.x;
  int a0 = (bb & 7) * 64, v0 = (bb >> 3) * 64;
#pragma unroll
  for (int l = 0; l < 4; ++l) {
    int idx = tid + l * 256;
    int r = idx >> 4, c = (idx & 15) * 4;
    float4 v = *(const float4*)(W + (long)(a0 + r) * Vsz + v0 + c);
    t[r][c] = v.x; t[r][c+1] = v.y; t[r][c+2] = v.z; t[r][c+3] = v.w;
  }
  __syncthreads();
#pragma unroll
  for (int l = 0; l < 4; ++l) {
    int idx = tid + l * 256;
    int r = idx >> 4, c = (idx & 15) * 4;   // r = v-local, c = a-local
    ushort4 h, lo;
    unsigned short* hp = (unsigned short*)&h;
    unsigned short* lp = (unsigned short*)&lo;
#pragma unroll
    for (int j = 0; j < 4; ++j) {
      float x = t[c + j][r];
      hp[j] = f2bf(x);
      lp[j] = f2bf(x - bf2f(hp[j]));
    }
    *(ushort4*)&WT_hi[(long)(v0 + r) * Asz + a0 + c] = h;
    *(ushort4*)&WT_lo[(long)(v0 + r) * Asz + a0 + c] = lo;
  }
}

// aM = AO @ W, 3-term split; 64x128 tile; lin_a fused (blockIdx.y==0).
// B via swizzled-source gld_lds; A direct-to-reg f32 split.
__global__ __launch_bounds__(256) void gemm_aM(
    const float* __restrict__ AO, const unsigned short* __restrict__ WT_hi,
    const unsigned short* __restrict__ WT_lo, const float* __restrict__ a_w,
    unsigned short* __restrict__ aM_hi, unsigned short* __restrict__ aM_lo,
    float* __restrict__ lin_a)
{
  __shared__ unsigned short b_hi[128][32];
  __shared__ unsigned short b_lo[128][32];
  int tid = threadIdx.x;
  int wave = tid >> 6, lane = tid & 63;
  int wr = wave >> 1, wc = wave & 1;
  int lr = lane & 15, kg = lane >> 4;
  long m0 = (long)blockIdx.x * 64;
  int  n0 = blockIdx.y * 128;
  bool doLin = (blockIdx.y == 0);
  f32x4 acc[2][4] = {};
  float lin[2] = {0.f, 0.f};
  for (int k0 = 0; k0 < Asz; k0 += 32) {
#pragma unroll
    for (int rep = 0; rep < 2; ++rep) {
      int i = rep * 256 + tid;
      int r = i >> 2, c8 = i & 3;
      int cs = (c8 ^ ((r >> 1) & 3)) * 8;            // swizzled source granule
      long off = (long)(n0 + r) * Asz + k0 + cs;
      gld16(WT_hi + off, (char*)&b_hi[0][0] + (rep * 4 + wave) * 1024);
      gld16(WT_lo + off, (char*)&b_lo[0][0] + (rep * 4 + wave) * 1024);
    }
    float4 aw0 = {0,0,0,0}, aw1 = {0,0,0,0};
    if (doLin) {
      aw0 = *(const float4*)(a_w + k0 + kg * 8);
      aw1 = *(const float4*)(a_w + k0 + kg * 8 + 4);
    }
    Frag2 a[2];
#pragma unroll
    for (int m = 0; m < 2; ++m) {
      const float* p = AO + (m0 + wr * 32 + m * 16 + lr) * Asz + k0 + kg * 8;
      float4 x0 = *(const float4*)p, x1 = *(const float4*)(p + 4);
      a[m] = split8(x0, x1);
      if (doLin) lin[m] += dot8(x0, x1, aw0, aw1);
    }
    __syncthreads();
    bh8 bh_[4], bl[4];
#pragma unroll
    for (int n = 0; n < 4; ++n) {
      int row = wc * 64 + n * 16 + lr;
      int cs = (kg ^ ((lr >> 1) & 3)) * 8;           // swizzled read granule
      bh_[n] = *(const bh8*)&b_hi[row][cs];
      bl[n]  = *(const bh8*)&b_lo[row][cs];
    }
#pragma unroll
    for (int m = 0; m < 2; ++m)
#pragma unroll
      for (int n = 0; n < 4; ++n) {
        acc[m][n] = __builtin_amdgcn_mfma_f32_16x16x32_bf16(a[m].hi, bh_[n], acc[m][n], 0, 0, 0);
        acc[m][n] = __builtin_amdgcn_mfma_f32_16x16x32_bf16(a[m].hi, bl[n],  acc[m][n], 0, 0, 0);
        acc[m][n] = __builtin_amdgcn_mfma_f32_16x16x32_bf16(a[m].lo, bh_[n], acc[m][n], 0, 0, 0);
      }
    __syncthreads();
  }
  if (doLin) {
#pragma unroll
    for (int m = 0; m < 2; ++m) {
      float v = lin[m];
      v += __shfl_xor(v, 16);
      v += __shfl_xor(v, 32);
      if (wc == 0 && lane < 16) lin_a[m0 + wr * 32 + m * 16 + lr] = v;
    }
  }
#pragma unroll
  for (int m = 0; m < 2; ++m)
#pragma unroll
    for (int n = 0; n < 4; ++n)
#pragma unroll
      for (int j = 0; j < 4; ++j) {
        float x = acc[m][n][j];
        unsigned int u = __float_as_uint(x);
        unsigned short h = (unsigned short)(u >> 16);
        float lof = x - __uint_as_float(u & 0xffff0000u);
        unsigned short l = (unsigned short)(__float_as_uint(lof) >> 16);
        long row = m0 + wr * 32 + m * 16 + kg * 4 + j;
        int  col = n0 + wc * 64 + n * 16 + lr;
        aM_hi[row * Asz + col] = h;
        aM_lo[row * Asz + col] = l;
      }
}

// sim tile (32 t x 128 n), 3-term split; lin_b fused; swizzled B gld;
// +lin+bias, tanh, masked softmax over n -> attn bf16
__global__ __launch_bounds__(256) void sim_fused(
    const float* __restrict__ inputs, const unsigned short* __restrict__ aMh,
    const unsigned short* __restrict__ aMl, const float* __restrict__ lin_a,
    const float* __restrict__ b_w, const int* __restrict__ mask,
    const float* __restrict__ bias, unsigned short* __restrict__ attn_bf)
{
  __shared__ union SU {
    struct { unsigned short b_hi[128][32], b_lo[128][32]; } st;
    float S[32][132];
  } u;
  __shared__ float linb_s[32];
  int b = blockIdx.y;
  int t0 = blockIdx.x * 32;
  int tid = threadIdx.x;
  int wave = tid >> 6, lane = tid & 63;
  int wr = wave >> 1, wc = wave & 1;   // wave: 16 t-rows x 64 n-cols
  int lr = lane & 15, kg = lane >> 4;
  const float* Ap = inputs + ((long)b * Tsz + t0) * Vsz;
  const unsigned short* Bh = aMh + (long)b * Nsz * Vsz;
  const unsigned short* Bl = aMl + (long)b * Nsz * Vsz;
  f32x4 acc[4] = {};
  float linb = 0.f;
  for (int k0 = 0; k0 < Vsz; k0 += 32) {
#pragma unroll
    for (int rep = 0; rep < 2; ++rep) {
      int i = rep * 256 + tid;
      int r = i >> 2, c8 = i & 3;
      int cs = (c8 ^ ((r >> 1) & 3)) * 8;
      long off = (long)r * Vsz + k0 + cs;
      gld16(Bh + off, (char*)&u.st.b_hi[0][0] + (rep * 4 + wave) * 1024);
      gld16(Bl + off, (char*)&u.st.b_lo[0][0] + (rep * 4 + wave) * 1024);
    }
    const float* p = Ap + (long)(wr * 16 + lr) * Vsz + k0 + kg * 8;
    float4 x0 = *(const float4*)p, x1 = *(const float4*)(p + 4);
    Frag2 a = split8(x0, x1);
    if (wc == 0) {
      float4 bw0 = *(const float4*)(b_w + k0 + kg * 8);
      float4 bw1 = *(const float4*)(b_w + k0 + kg * 8 + 4);
      linb += dot8(x0, x1, bw0, bw1);
    }
    __syncthreads();
    bh8 bh_[4], bl[4];
#pragma unroll
    for (int n = 0; n < 4; ++n) {
      int row = wc * 64 + n * 16 + lr;
      int cs = (kg ^ ((lr >> 1) & 3)) * 8;
      bh_[n] = *(const bh8*)&u.st.b_hi[row][cs];
      bl[n]  = *(const bh8*)&u.st.b_lo[row][cs];
    }
#pragma unroll
    for (int n = 0; n < 4; ++n) {
      acc[n] = __builtin_amdgcn_mfma_f32_16x16x32_bf16(a.hi, bh_[n], acc[n], 0, 0, 0);
      acc[n] = __builtin_amdgcn_mfma_f32_16x16x32_bf16(a.hi, bl[n],  acc[n], 0, 0, 0);
      acc[n] = __builtin_amdgcn_mfma_f32_16x16x32_bf16(a.lo, bh_[n], acc[n], 0, 0, 0);
    }
    __syncthreads();
  }
  if (wc == 0) {
    float v = linb;
    v += __shfl_xor(v, 16);
    v += __shfl_xor(v, 32);
    if (lane < 16) linb_s[wr * 16 + lr] = v;
  }
#pragma unroll
  for (int n = 0; n < 4; ++n)
#pragma unroll
    for (int j = 0; j < 4; ++j)
      u.S[wr * 16 + kg * 4 + j][wc * 64 + n * 16 + lr] = acc[n][j];
  __syncthreads();

  float la0 = lin_a[b * Nsz + lane];
  float la1 = lin_a[b * Nsz + 64 + lane];
  int   mk0 = mask[b * Nsz + lane];
  int   mk1 = mask[b * Nsz + 64 + lane];
  float bs  = bias[0];
#pragma unroll
  for (int rr = 0; rr < 8; ++rr) {
    int r = wave * 8 + rr;
    int tI = t0 + r;
    float lb = linb_s[r] + bs;
    float s0 = u.S[r][lane] + la0 + lb;
    float s1 = u.S[r][64 + lane] + la1 + lb;
    s0 = fast_tanh(s0); s1 = fast_tanh(s1);
    float v0 = mk0 ? s0 : -1e30f;
    float v1 = mk1 ? s1 : -1e30f;
    float mx = fmaxf(v0, v1);
#pragma unroll
    for (int off = 32; off; off >>= 1) mx = fmaxf(mx, __shfl_xor(mx, off));
    float e0 = mk0 ? __expf(v0 - mx) : 0.f;
    float e1 = mk1 ? __expf(v1 - mx) : 0.f;
    float sm = e0 + e1;
#pragma unroll
    for (int off = 32; off; off >>= 1) sm += __shfl_xor(sm, off);
    float inv = 1.f / sm;
    long base = ((long)b * Tsz + tI) * Nsz;
    attn_bf[base + lane]      = f2bf(e0 * inv);
    attn_bf[base + 64 + lane] = f2bf(e1 * inv);
  }
}

// AO[b][n][a] f32 -> AOt[b][a][n] bf16 (XOR-swizzled LDS transpose)
__global__ __launch_bounds__(256) void ao_transpose(
    const float* __restrict__ AO, unsigned short* __restrict__ AOt)
{
  __shared__ unsigned short t[128][128];
  int b = blockIdx.x >> 2;
  int a0 = (blockIdx.x & 3) * 128;
  int tid = threadIdx.x;
#pragma unroll
  for (int l = 0; l < 16; ++l) {
    int idx = tid + l * 256;
    int r = idx >> 5, c = (idx & 31) * 4;
    float4 v = *(const float4*)(AO + ((long)b * Nsz + r) * Asz + a0 + c);
    ushort4 h;
    unsigned short* hp = (unsigned short*)&h;
    hp[0] = f2bf(v.x); hp[1] = f2bf(v.y); hp[2] = f2bf(v.z); hp[3] = f2bf(v.w);
    int key = ((r >> 3) & 7) << 2;
    *(ushort4*)&t[r][c ^ key] = h;
  }
  __syncthreads();
#pragma unroll
  for (int l = 0; l < 8; ++l) {
    int idx = tid + l * 256;
    int ra = idx >> 4, cc = idx & 15;
    int key = (cc & 7) << 2;
    union { unsigned short s[8]; uint4 q; } g;
#pragma unroll
    for (int j = 0; j < 8; ++j) g.s[j] = t[cc * 8 + j][ra ^ key];
    *(uint4*)&AOt[((long)b * Asz + a0 + ra) * Nsz + cc * 8] = g.q;
  }
}

// context = attn(bf16) @ AO via AOt; both via swizzled gld_lds
__global__ __launch_bounds__(256) void gemm_ctx(
    const unsigned short* __restrict__ attn_bf, const unsigned short* __restrict__ AOt,
    float* __restrict__ out)
{
  __shared__ unsigned short a_t[128][32];
  __shared__ unsigned short b_t[128][32];
  int b = blockIdx.z;
  int m0 = blockIdx.x * 128, n0 = blockIdx.y * 128;
  int tid = threadIdx.x;
  int wave = tid >> 6, lane = tid & 63;
  int wr = wave >> 1, wc = wave & 1;
  int lr = lane & 15, kg = lane >> 4;
  const unsigned short* Ap = attn_bf + (long)b * Tsz * Nsz;
  const unsigned short* Bp = AOt + (long)b * Asz * Nsz;
  f32x4 acc[4][4] = {};
  for (int k0 = 0; k0 < Nsz; k0 += 32) {
#pragma unroll
    for (int rep = 0; rep < 2; ++rep) {
      int i = rep * 256 + tid;
      int r = i >> 2, c8 = i & 3;
      int cs = (c8 ^ ((r >> 1) & 3)) * 8;
      gld16(Ap + (long)(m0 + r) * Nsz + k0 + cs, (char*)&a_t[0][0] + (rep * 4 + wave) * 1024);
      gld16(Bp + (long)(n0 + r) * Nsz + k0 + cs, (char*)&b_t[0][0] + (rep * 4 + wave) * 1024);
    }
    __syncthreads();
    bh8 af[4], bf_[4];
    int cs = (kg ^ ((lr >> 1) & 3)) * 8;
#pragma unroll
    for (int m = 0; m < 4; ++m) af[m] = *(const bh8*)&a_t[wr * 64 + m * 16 + lr][cs];
#pragma unroll
    for (int n = 0; n < 4; ++n) bf_[n] = *(const bh8*)&b_t[wc * 64 + n * 16 + lr][cs];
#pragma unroll
    for (int m = 0; m < 4; ++m)
#pragma unroll
      for (int n = 0; n < 4; ++n)
        acc[m][n] = __builtin_amdgcn_mfma_f32_16x16x32_bf16(af[m], bf_[n], acc[m][n], 0, 0, 0);
    __syncthreads();
  }
#pragma unroll
  for (int m = 0; m < 4; ++m)
#pragma unroll
    for (int n = 0; n < 4; ++n)
#pragma unroll
      for (int j = 0; j < 4; ++j)
        out[((long)b * Tsz + m0 + wr * 64 + m * 16 + kg * 4 + j) * Asz + n0 + wc * 64 + n * 16 + lr]
          = acc[m][n][j];
}

extern "C" void kernel_launch(void* const* d_in, const int* in_sizes, int n_in,
                              void* d_out, int out_size, void* d_ws, size_t ws_size,
                              hipStream_t stream) {
  const float* inputs = (const float*)d_in[0];
  const float* AO     = (const float*)d_in[1];
  const int*   mask   = (const int*)d_in[2];
  const float* W      = (const float*)d_in[3];
  const float* a_w    = (const float*)d_in[4];
  const float* b_w    = (const float*)d_in[5];
  const float* bias   = (const float*)d_in[6];
  float* out = (float*)d_out;
  char* wsb  = (char*)d_ws;

  unsigned short* aM_hi   = (unsigned short*)wsb;                 // 16,777,216 B
  unsigned short* aM_lo   = (unsigned short*)(wsb + 16777216);    // 16,777,216 B
  unsigned short* AOt     = (unsigned short*)wsb;                 // overlaps aM_hi (after sim)
  unsigned short* WT_hi   = (unsigned short*)(wsb + 33554432);    // 524,288 B
  unsigned short* WT_lo   = (unsigned short*)(wsb + 34078720);    // 524,288 B
  float*          lin_a   = (float*)(wsb + 34603008);             // 65,536 B
  unsigned short* attn_bf = (unsigned short*)(wsb + 34799616);    // 8,388,608 B

  prep_wt<<<64, 256, 0, stream>>>(W, WT_hi, WT_lo);
  gemm_aM<<<dim3(256, 4), 256, 0, stream>>>(AO, WT_hi, WT_lo, a_w, aM_hi, aM_lo, lin_a);
  sim_fused<<<dim3(8, 128), 256, 0, stream>>>(inputs, aM_hi, aM_lo, lin_a, b_w, mask, bias, attn_bf);
  ao_transpose<<<512, 256, 0, stream>>>(AO, AOt);
  gemm_ctx<<<dim3(2, 4, 128), 256, 0, stream>>>(attn_bf, AOt, out);
}